// Round 1
// baseline (1846.830 us; speedup 1.0000x reference)
//
#include <hip/hip_runtime.h>
#include <hip/hip_bf16.h>

#define B_    2
#define L_    2048
#define D_    4096
#define F_    11008
#define M_TOK (B_ * L_)          // 4096 tokens
#define BM    128
#define M_ALLOC (M_TOK + BM)     // 4224 slots: vision [0,nv), gap of 128, language at top
#define BK    64
#define NTM   (M_ALLOC / BM)     // 33 M-tiles

typedef __attribute__((ext_vector_type(8))) __bf16 bf16x8;
typedef __attribute__((ext_vector_type(4))) float  f32x4;

// ---------------------------------------------------------------- utilities

__device__ __forceinline__ void gload_lds16(const void* g, void* l) {
  __builtin_amdgcn_global_load_lds(
      (const __attribute__((address_space(1))) void*)g,
      (__attribute__((address_space(3))) void*)l, 16, 0, 0);
}

// stage a 128x64 bf16 tile (global row stride = ld elems) into LDS [128][64]
__device__ __forceinline__ void stage_128x64(const __hip_bfloat16* __restrict__ src,
                                             size_t ld, __bf16* lds, int tid) {
  const int lane = tid & 63;
  const int wv   = tid >> 6;
#pragma unroll
  for (int p = 0; p < 4; ++p) {
    const int chunk = wv * 4 + p;              // 16 chunks x 1KB
    const int row   = chunk * 8 + (lane >> 3); // 8 rows per chunk
    const int col   = (lane & 7) * 8;          // 8 bf16 = 16B per lane
    gload_lds16(src + (size_t)row * ld + col, lds + chunk * 512);
  }
}

// ---------------------------------------------------------------- preprocessing

__global__ void init_kernel(int* counters, int* slot2tok) {
  int i = blockIdx.x * 256 + threadIdx.x;
  if (i < 2) counters[i] = 0;
  if (i < M_ALLOC) slot2tok[i] = -1;
}

__global__ void assign_kernel(const int* __restrict__ tt, int* counters,
                              int* __restrict__ slot2tok) {
  int t = blockIdx.x * 256 + threadIdx.x;
  if (t >= M_TOK) return;
  int l = t & (L_ - 1);
  bool isv = (tt[t] == 1) && (l < L_ - 1) && (tt[t + 1] == 1);
  int slot;
  if (isv) slot = atomicAdd(&counters[0], 1);
  else     slot = M_ALLOC - 1 - atomicAdd(&counters[1], 1);
  slot2tok[slot] = t;
}

// gather hidden_states rows into bf16 slot order; zero the gap rows
__global__ void gather_cvt(const float* __restrict__ x, const int* __restrict__ slot2tok,
                           __hip_bfloat16* __restrict__ xg) {
  const int s = blockIdx.x;
  const int t = slot2tok[s];
  __hip_bfloat16* dst = xg + (size_t)s * D_ + threadIdx.x * 16;
  union { __hip_bfloat16 h[8]; uint4 v; } p0, p1;
  if (t >= 0) {
    const float* sp = x + (size_t)t * D_ + threadIdx.x * 16;
    const float4* s4 = (const float4*)sp;
    float4 a = s4[0], b = s4[1], c = s4[2], d = s4[3];
    float vals[16] = {a.x,a.y,a.z,a.w,b.x,b.y,b.z,b.w,c.x,c.y,c.z,c.w,d.x,d.y,d.z,d.w};
#pragma unroll
    for (int i = 0; i < 8; ++i) p0.h[i] = __float2bfloat16(vals[i]);
#pragma unroll
    for (int i = 0; i < 8; ++i) p1.h[i] = __float2bfloat16(vals[8 + i]);
  } else {
    p0.v = make_uint4(0, 0, 0, 0);
    p1.v = make_uint4(0, 0, 0, 0);
  }
  *(uint4*)dst       = p0.v;
  *(uint4*)(dst + 8) = p1.v;
}

// f32 [R][C] -> bf16 [C][R]
__global__ void transpose_cvt(const float* __restrict__ in, __hip_bfloat16* __restrict__ out,
                              int R, int C) {
  __shared__ float t[32][33];
  const int c0 = blockIdx.x * 32, r0 = blockIdx.y * 32;
  const int tx = threadIdx.x, ty = threadIdx.y; // (32, 8)
#pragma unroll
  for (int i = 0; i < 32; i += 8)
    t[ty + i][tx] = in[(size_t)(r0 + ty + i) * C + c0 + tx];
  __syncthreads();
#pragma unroll
  for (int i = 0; i < 32; i += 8)
    out[(size_t)(c0 + ty + i) * R + r0 + tx] = __float2bfloat16(t[tx][ty + i]);
}

__global__ void sentinel_kernel(float* out, int n) {
  int i = blockIdx.x * 256 + threadIdx.x;
  if (i < n) out[i] = 1e30f;
}

// ---------------------------------------------------------------- GEMM 1: gate+up fused

__global__ __launch_bounds__(256, 2) void gemm_gateup(
    const __hip_bfloat16* __restrict__ Xg,
    const __hip_bfloat16* __restrict__ Wg_v, const __hip_bfloat16* __restrict__ Wu_v,
    const __hip_bfloat16* __restrict__ Wg_l, const __hip_bfloat16* __restrict__ Wu_l,
    __hip_bfloat16* __restrict__ H, const int* __restrict__ counters) {
  __shared__ __bf16 As[128 * 64];
  __shared__ __bf16 Bgs[128 * 64];
  __shared__ __bf16 Bus[128 * 64];
  const int tid = threadIdx.x;
  const int lane = tid & 63;
  const int wv = tid >> 6, wm = wv >> 1, wn = wv & 1;
  const int l15 = lane & 15, l4 = lane >> 4;
  const int row0 = blockIdx.y * BM;
  const int col0 = blockIdx.x * BM;
  const int nv = counters[0];
  const __hip_bfloat16* Bg = (row0 < nv) ? Wg_v : Wg_l;
  const __hip_bfloat16* Bu = (row0 < nv) ? Wu_v : Wu_l;
  const __hip_bfloat16* As_g = Xg + (size_t)row0 * D_;
  const __hip_bfloat16* Bg_g = Bg + (size_t)col0 * D_;
  const __hip_bfloat16* Bu_g = Bu + (size_t)col0 * D_;

  f32x4 accg[4][4] = {};
  f32x4 accu[4][4] = {};

  for (int k0 = 0; k0 < D_; k0 += BK) {
    stage_128x64(As_g + k0, D_, As, tid);
    stage_128x64(Bg_g + k0, D_, Bgs, tid);
    stage_128x64(Bu_g + k0, D_, Bus, tid);
    asm volatile("s_waitcnt vmcnt(0)" ::: "memory");
    __syncthreads();
#pragma unroll
    for (int ks = 0; ks < 2; ++ks) {
      const int koff = ks * 32 + l4 * 8;
      bf16x8 af[4], bgf[4], buf2[4];
#pragma unroll
      for (int i = 0; i < 4; ++i) {
        af[i]   = *(const bf16x8*)(As  + (wm * 64 + i * 16 + l15) * 64 + koff);
        bgf[i]  = *(const bf16x8*)(Bgs + (wn * 64 + i * 16 + l15) * 64 + koff);
        buf2[i] = *(const bf16x8*)(Bus + (wn * 64 + i * 16 + l15) * 64 + koff);
      }
#pragma unroll
      for (int m = 0; m < 4; ++m)
#pragma unroll
        for (int n = 0; n < 4; ++n) {
          accg[m][n] = __builtin_amdgcn_mfma_f32_16x16x32_bf16(af[m], bgf[n], accg[m][n], 0, 0, 0);
          accu[m][n] = __builtin_amdgcn_mfma_f32_16x16x32_bf16(af[m], buf2[n], accu[m][n], 0, 0, 0);
        }
    }
    __syncthreads();
  }
  // epilogue: h = silu(g) * u, bf16 store
#pragma unroll
  for (int m = 0; m < 4; ++m)
#pragma unroll
    for (int n = 0; n < 4; ++n)
#pragma unroll
      for (int r = 0; r < 4; ++r) {
        const int row = row0 + wm * 64 + m * 16 + l4 * 4 + r;
        const int col = col0 + wn * 64 + n * 16 + l15;
        const float g = accg[m][n][r];
        const float u = accu[m][n][r];
        const float s = g / (1.0f + __expf(-g));
        H[(size_t)row * F_ + col] = __float2bfloat16(s * u);
      }
}

// ---------------------------------------------------------------- GEMM 2: down + scatter

__global__ __launch_bounds__(256, 2) void gemm_down(
    const __hip_bfloat16* __restrict__ Hm,
    const __hip_bfloat16* __restrict__ Wd_v, const __hip_bfloat16* __restrict__ Wd_l,
    float* __restrict__ out, const int* __restrict__ counters,
    const int* __restrict__ slot2tok) {
  __shared__ __bf16 As[128 * 64];
  __shared__ __bf16 Bs[128 * 64];
  const int tid = threadIdx.x;
  const int lane = tid & 63;
  const int wv = tid >> 6, wm = wv >> 1, wn = wv & 1;
  const int l15 = lane & 15, l4 = lane >> 4;
  const int row0 = blockIdx.y * BM;
  const int col0 = blockIdx.x * BM;
  const int nv = counters[0];
  const __hip_bfloat16* Bd = (row0 < nv) ? Wd_v : Wd_l;
  const __hip_bfloat16* As_g = Hm + (size_t)row0 * F_;
  const __hip_bfloat16* Bd_g = Bd + (size_t)col0 * F_;

  f32x4 acc[4][4] = {};

  for (int k0 = 0; k0 < F_; k0 += BK) {
    stage_128x64(As_g + k0, F_, As, tid);
    stage_128x64(Bd_g + k0, F_, Bs, tid);
    asm volatile("s_waitcnt vmcnt(0)" ::: "memory");
    __syncthreads();
#pragma unroll
    for (int ks = 0; ks < 2; ++ks) {
      const int koff = ks * 32 + l4 * 8;
      bf16x8 af[4], bf_[4];
#pragma unroll
      for (int i = 0; i < 4; ++i) {
        af[i]  = *(const bf16x8*)(As + (wm * 64 + i * 16 + l15) * 64 + koff);
        bf_[i] = *(const bf16x8*)(Bs + (wn * 64 + i * 16 + l15) * 64 + koff);
      }
#pragma unroll
      for (int m = 0; m < 4; ++m)
#pragma unroll
        for (int n = 0; n < 4; ++n)
          acc[m][n] = __builtin_amdgcn_mfma_f32_16x16x32_bf16(af[m], bf_[n], acc[m][n], 0, 0, 0);
    }
    __syncthreads();
  }
  // epilogue: scatter rows back to token order (f32 out)
#pragma unroll
  for (int m = 0; m < 4; ++m)
#pragma unroll
    for (int r = 0; r < 4; ++r) {
      const int slot = row0 + wm * 64 + m * 16 + l4 * 4 + r;
      const int tok = slot2tok[slot];
      if (tok < 0) continue;
      float* orow = out + (size_t)tok * D_;
#pragma unroll
      for (int n = 0; n < 4; ++n) {
        const int col = col0 + wn * 64 + n * 16 + l15;
        orow[col] = acc[m][n][r];
      }
    }
}

// ---------------------------------------------------------------- host

extern "C" void kernel_launch(void* const* d_in, const int* in_sizes, int n_in,
                              void* d_out, int out_size, void* d_ws, size_t ws_size,
                              hipStream_t stream) {
  const float* x   = (const float*)d_in[0];
  const int*   tt  = (const int*)d_in[1];
  const float* wgv = (const float*)d_in[2];
  const float* wuv = (const float*)d_in[3];
  const float* wdv = (const float*)d_in[4];
  const float* wgl = (const float*)d_in[5];
  const float* wul = (const float*)d_in[6];
  const float* wdl = (const float*)d_in[7];
  float* out = (float*)d_out;

  // workspace layout
  size_t off = 0;
  auto nalign = [](size_t v) { return (v + 255) & ~(size_t)255; };
  const size_t o_cnt = off; off += nalign(2 * sizeof(int));
  const size_t o_s2t = off; off += nalign((size_t)M_ALLOC * sizeof(int));
  const size_t o_xg  = off; off += nalign((size_t)M_ALLOC * D_ * 2);
  const size_t o_h   = off; off += nalign((size_t)M_ALLOC * F_ * 2);
  const size_t wbytes = nalign((size_t)D_ * F_ * 2);
  const size_t o_wgv = off; off += wbytes;  // gate_v^T  [F][D] bf16
  const size_t o_wuv = off; off += wbytes;  // up_v^T    [F][D]
  const size_t o_wgl = off; off += wbytes;  // gate_l^T  [F][D]
  const size_t o_wul = off; off += wbytes;  // up_l^T    [F][D]
  const size_t o_wdv = off; off += wbytes;  // down_v^T  [D][F]
  const size_t o_wdl = off; off += wbytes;  // down_l^T  [D][F]

  if (ws_size < off) {  // unambiguous signal: ws too small for this design
    sentinel_kernel<<<(out_size + 255) / 256, 256, 0, stream>>>(out, out_size);
    return;
  }

  char* ws = (char*)d_ws;
  int* counters = (int*)(ws + o_cnt);
  int* slot2tok = (int*)(ws + o_s2t);
  __hip_bfloat16* Xg  = (__hip_bfloat16*)(ws + o_xg);
  __hip_bfloat16* H   = (__hip_bfloat16*)(ws + o_h);
  __hip_bfloat16* Wgv = (__hip_bfloat16*)(ws + o_wgv);
  __hip_bfloat16* Wuv = (__hip_bfloat16*)(ws + o_wuv);
  __hip_bfloat16* Wgl = (__hip_bfloat16*)(ws + o_wgl);
  __hip_bfloat16* Wul = (__hip_bfloat16*)(ws + o_wul);
  __hip_bfloat16* Wdv = (__hip_bfloat16*)(ws + o_wdv);
  __hip_bfloat16* Wdl = (__hip_bfloat16*)(ws + o_wdl);

  // 1. init + slot assignment
  init_kernel<<<(M_ALLOC + 255) / 256, 256, 0, stream>>>(counters, slot2tok);
  assign_kernel<<<(M_TOK + 255) / 256, 256, 0, stream>>>(tt, counters, slot2tok);

  // 2. gather tokens to bf16 slot rows
  gather_cvt<<<M_ALLOC, 256, 0, stream>>>(x, slot2tok, Xg);

  // 3. convert+transpose weights to bf16 [N][K]
  dim3 tb(32, 8);
  dim3 tg_gu(F_ / 32, D_ / 32);   // in [D][F] -> out [F][D]
  dim3 tg_dn(D_ / 32, F_ / 32);   // in [F][D] -> out [D][F]
  transpose_cvt<<<tg_gu, tb, 0, stream>>>(wgv, Wgv, D_, F_);
  transpose_cvt<<<tg_gu, tb, 0, stream>>>(wuv, Wuv, D_, F_);
  transpose_cvt<<<tg_gu, tb, 0, stream>>>(wgl, Wgl, D_, F_);
  transpose_cvt<<<tg_gu, tb, 0, stream>>>(wul, Wul, D_, F_);
  transpose_cvt<<<tg_dn, tb, 0, stream>>>(wdv, Wdv, F_, D_);
  transpose_cvt<<<tg_dn, tb, 0, stream>>>(wdl, Wdl, F_, D_);

  // 4. H = silu(Xg*Wg) * (Xg*Wu), expert-pure per 128-row tile
  gemm_gateup<<<dim3(F_ / BM, NTM), 256, 0, stream>>>(Xg, Wgv, Wuv, Wgl, Wul, H, counters);

  // 5. out[token] = H * Wd (scatter epilogue)
  gemm_down<<<dim3(D_ / BM, NTM), 256, 0, stream>>>(H, Wdv, Wdl, out, counters, slot2tok);
}

// Round 3
// 1697.235 us; speedup vs baseline: 1.0881x; 1.0881x over previous
//
#include <hip/hip_runtime.h>
#include <hip/hip_bf16.h>

#define B_    2
#define L_    2048
#define D_    4096
#define F_    11008
#define M_TOK (B_ * L_)          // 4096 tokens
#define BM    256
#define M_ALLOC (M_TOK + BM)     // 4352: vision [0,nv), 256-gap, language at top
#define NTM   (M_ALLOC / BM)     // 17 M-tiles
#define NT_GU (D_ / 64)          // 64 K-tiles for gate/up
#define NT_DN (F_ / 64)          // 172 K-tiles for down
#define NTILE_GU (2 * F_ / 256)  // 86 N-tiles (gate|up concat)
#define GATE_TILES (F_ / 256)    // 43
#define LDS_BYTES 131072

typedef __attribute__((ext_vector_type(8))) __bf16 bf16x8;
typedef __attribute__((ext_vector_type(4))) float  f32x4;
typedef unsigned short ushort_t;
typedef unsigned int   uint_t;

// ---------------------------------------------------------------- primitives

__device__ __forceinline__ void gload_lds16(const void* g, void* l) {
  __builtin_amdgcn_global_load_lds(
      (const __attribute__((address_space(1))) void*)g,
      (__attribute__((address_space(3))) void*)l, 16, 0, 0);
}

#define PH_BAR()  { __builtin_amdgcn_sched_barrier(0); __builtin_amdgcn_s_barrier(); __builtin_amdgcn_sched_barrier(0); }
#define LGKM0()   { asm volatile("s_waitcnt lgkmcnt(0)" ::: "memory"); __builtin_amdgcn_sched_barrier(0); }
#define VM4()     { asm volatile("s_waitcnt vmcnt(4)" ::: "memory"); __builtin_amdgcn_sched_barrier(0); }
#define VM0()     { asm volatile("s_waitcnt vmcnt(0)" ::: "memory"); __builtin_amdgcn_sched_barrier(0); }

__device__ __forceinline__ ushort_t f2bf(float v) {
  union { __hip_bfloat16 h; ushort_t u; } cv;
  cv.h = __float2bfloat16(v);
  return cv.u;
}

// stage one 128x64 bf16 half-tile, inverse-swizzled source -> linear LDS.
// Swizzle (involution): byte ^= (row&7)<<4  <=>  chunk-in-row ^= row&7.
__device__ __forceinline__ void stage_half(const __hip_bfloat16* __restrict__ src, int ldE,
                                           __bf16* ldsb, int w, int lane) {
#pragma unroll
  for (int j = 0; j < 2; ++j) {
    const int ch  = (w * 2 + j) * 64 + lane;   // 16B chunk id, 0..1023
    const int row = ch >> 3;                   // 0..127
    const int cc  = (ch & 7) ^ (row & 7);      // pre-swizzled col chunk
    gload_lds16(src + (size_t)(row * ldE + cc * 8), ldsb + (w * 2 + j) * 512);
  }
}

// swizzled ds_read_b128 of one MFMA fragment from a [rows][64] bf16 region
__device__ __forceinline__ bf16x8 ldfrag(const __bf16* region, int row, int koffb) {
  const int off = ((row << 7) + koffb) ^ ((row & 7) << 4);
  return *(const bf16x8*)((const char*)region + off);
}

__device__ __forceinline__ void mfma_q(f32x4 (&acc)[8][4], int mb, int nb,
                                       const bf16x8 (&af)[4][2], const bf16x8 (&bf)[2][2]) {
#pragma unroll
  for (int mm = 0; mm < 4; ++mm)
#pragma unroll
    for (int nn = 0; nn < 2; ++nn)
#pragma unroll
      for (int ks = 0; ks < 2; ++ks)
        acc[mb + mm][nb + nn] = __builtin_amdgcn_mfma_f32_16x16x32_bf16(
            af[mm][ks], bf[nn][ks], acc[mb + mm][nb + nn], 0, 0, 0);
}

// 256x256 tile, 8 waves (2Mx4N), per-wave 128x64. 4 phases per K-tile.
// Stage plan: P1:B0(t+1) P2:B1(t+1) P3:A0(t+2) P4:A1(t+2).
// vmcnt ledger: tile start = 4 outstanding (A(t+1)); +8 during tile; end-wait
// must retire A(t+1)+B(t+1) => vmcnt(4) while A(t+2) was staged, ELSE vmcnt(0)
// (tail tiles: leaving vmcnt(4) would keep B(nt-1) in flight -> stale reads;
//  this was the round-2 correctness bug).
__device__ __forceinline__ void gemm_kloop(const __hip_bfloat16* __restrict__ Ag, const int ldA,
                                           const __hip_bfloat16* __restrict__ Bg, const int ldB,
                                           const int nt, __bf16* smem, f32x4 (&acc)[8][4],
                                           const int wm, const int wn, const int l15,
                                           const int l4, const int w, const int lane) {
  // prologue issue order: A0(0) A1(0) B0(0) B1(0) A0(1) A1(1)
  stage_half(Ag,             ldA, smem,                w, lane);
  stage_half(Ag + 128 * ldA, ldA, smem + 8192,         w, lane);
  stage_half(Bg,             ldB, smem + 16384,        w, lane);
  stage_half(Bg + 128 * ldB, ldB, smem + 24576,        w, lane);
  if (1 < nt) {
    stage_half(Ag + 64,             ldA, smem + 32768,        w, lane);
    stage_half(Ag + 64 + 128 * ldA, ldA, smem + 32768 + 8192, w, lane);
  }
  VM4(); PH_BAR();

  for (int t = 0; t < nt; ++t) {
    __bf16* bufc = smem + (t & 1) * 32768;
    __bf16* bufn = smem + ((t + 1) & 1) * 32768;
    const __bf16* At = bufc;
    const __bf16* Bt = bufc + 16384;
    bf16x8 a0[4][2], a1[4][2], b0[2][2], b1[2][2];

    // ---- P1: ds_read A-mh0 + B-nh0; stage B-half0(t+1)
#pragma unroll
    for (int i = 0; i < 4; ++i)
#pragma unroll
      for (int ks = 0; ks < 2; ++ks)
        a0[i][ks] = ldfrag(At, wm * 128 + i * 16 + l15, ks * 64 + l4 * 16);
#pragma unroll
    for (int n = 0; n < 2; ++n)
#pragma unroll
      for (int ks = 0; ks < 2; ++ks)
        b0[n][ks] = ldfrag(Bt, wn * 64 + n * 16 + l15, ks * 64 + l4 * 16);
    if (t + 1 < nt) stage_half(Bg + (t + 1) * 64, ldB, bufn + 16384, w, lane);
    PH_BAR(); LGKM0();
    __builtin_amdgcn_s_setprio(1);
    mfma_q(acc, 0, 0, a0, b0);
    __builtin_amdgcn_s_setprio(0);
    PH_BAR();

    // ---- P2: ds_read A-mh1; stage B-half1(t+1)
#pragma unroll
    for (int i = 0; i < 4; ++i)
#pragma unroll
      for (int ks = 0; ks < 2; ++ks)
        a1[i][ks] = ldfrag(At, wm * 128 + 64 + i * 16 + l15, ks * 64 + l4 * 16);
    if (t + 1 < nt) stage_half(Bg + (t + 1) * 64 + 128 * ldB, ldB, bufn + 24576, w, lane);
    PH_BAR(); LGKM0();
    __builtin_amdgcn_s_setprio(1);
    mfma_q(acc, 4, 0, a1, b0);
    __builtin_amdgcn_s_setprio(0);
    PH_BAR();

    // ---- P3: ds_read B-nh1; stage A-half0(t+2)
#pragma unroll
    for (int n = 0; n < 2; ++n)
#pragma unroll
      for (int ks = 0; ks < 2; ++ks)
        b1[n][ks] = ldfrag(Bt, wn * 64 + 32 + n * 16 + l15, ks * 64 + l4 * 16);
    if (t + 2 < nt) stage_half(Ag + (t + 2) * 64, ldA, bufc, w, lane);
    PH_BAR(); LGKM0();
    __builtin_amdgcn_s_setprio(1);
    mfma_q(acc, 4, 2, a1, b1);
    __builtin_amdgcn_s_setprio(0);
    PH_BAR();

    // ---- P4: stage A-half1(t+2); MFMA mh0 x nh1 from registers
    if (t + 2 < nt) stage_half(Ag + (t + 2) * 64 + 128 * ldA, ldA, bufc + 8192, w, lane);
    __builtin_amdgcn_s_setprio(1);
    mfma_q(acc, 0, 2, a0, b1);
    __builtin_amdgcn_s_setprio(0);
    if (t + 2 < nt) { VM4(); } else { VM0(); }   // tail drain fix
    PH_BAR();
  }
}

// ---------------------------------------------------------------- preprocessing

__global__ void init_kernel(int* counters, int* slot2tok) {
  int i = blockIdx.x * 256 + threadIdx.x;
  if (i < 2) counters[i] = 0;
  if (i < M_ALLOC) slot2tok[i] = -1;
}

__global__ void assign_kernel(const int* __restrict__ tt, int* counters,
                              int* __restrict__ slot2tok) {
  int t = blockIdx.x * 256 + threadIdx.x;
  if (t >= M_TOK) return;
  int l = t & (L_ - 1);
  bool isv = (tt[t] == 1) && (l < L_ - 1) && (tt[t + 1] == 1);
  int slot;
  if (isv) slot = atomicAdd(&counters[0], 1);
  else     slot = M_ALLOC - 1 - atomicAdd(&counters[1], 1);
  slot2tok[slot] = t;
}

__global__ void gather_cvt(const float* __restrict__ x, const int* __restrict__ slot2tok,
                           __hip_bfloat16* __restrict__ xg) {
  const int s = blockIdx.x;
  const int t = slot2tok[s];
  __hip_bfloat16* dst = xg + (size_t)s * D_ + threadIdx.x * 16;
  union { ushort_t h[8]; uint4 v; } p0, p1;
  if (t >= 0) {
    const float4* s4 = (const float4*)(x + (size_t)t * D_ + threadIdx.x * 16);
    float4 a = s4[0], b = s4[1], c = s4[2], d = s4[3];
    float vals[16] = {a.x,a.y,a.z,a.w,b.x,b.y,b.z,b.w,c.x,c.y,c.z,c.w,d.x,d.y,d.z,d.w};
#pragma unroll
    for (int i = 0; i < 8; ++i) p0.h[i] = f2bf(vals[i]);
#pragma unroll
    for (int i = 0; i < 8; ++i) p1.h[i] = f2bf(vals[8 + i]);
  } else {
    p0.v = make_uint4(0, 0, 0, 0);
    p1.v = make_uint4(0, 0, 0, 0);
  }
  *(uint4*)dst = p0.v;
  *(uint4*)(dst + 8) = p1.v;
}

// f32 [R][C] -> bf16 [C][R]; coalesced reads, 64B/lane contiguous writes
__global__ __launch_bounds__(128) void transpose_cvt64(const float* __restrict__ in,
                                                       __hip_bfloat16* __restrict__ out,
                                                       int R, int C) {
  const int c  = threadIdx.x & 63;
  const int rc = threadIdx.x >> 6;
  const int c0 = blockIdx.x * 64;
  const int r0 = blockIdx.y * 64 + rc * 32;
  const float* ip = in + (size_t)r0 * C + c0 + c;
  uint_t pk[16];
#pragma unroll
  for (int j = 0; j < 16; ++j) {
    float v0 = ip[(size_t)(2 * j) * C];
    float v1 = ip[(size_t)(2 * j + 1) * C];
    pk[j] = (uint_t)f2bf(v0) | ((uint_t)f2bf(v1) << 16);
  }
  uint4* op = (uint4*)(out + (size_t)(c0 + c) * R + r0);
#pragma unroll
  for (int k = 0; k < 4; ++k)
    op[k] = make_uint4(pk[4 * k], pk[4 * k + 1], pk[4 * k + 2], pk[4 * k + 3]);
}

__global__ void silu_mul_kernel(__hip_bfloat16* __restrict__ G,
                                const __hip_bfloat16* __restrict__ U, long long n8) {
  long long i = (long long)blockIdx.x * 256 + threadIdx.x;
  if (i >= n8) return;
  union { uint4 v; ushort_t s[8]; } g, u, h;
  g.v = ((const uint4*)G)[i];
  u.v = ((const uint4*)U)[i];
#pragma unroll
  for (int k = 0; k < 8; ++k) {
    float gf = __uint_as_float((uint_t)g.s[k] << 16);
    float uf = __uint_as_float((uint_t)u.s[k] << 16);
    float s  = gf / (1.0f + __expf(-gf));
    h.s[k] = f2bf(s * uf);
  }
  ((uint4*)G)[i] = h.v;   // in-place: G becomes H
}

__global__ void sentinel_kernel(float* out, int n) {
  int i = blockIdx.x * 256 + threadIdx.x;
  if (i < n) out[i] = 1e30f;
}

// ---------------------------------------------------------------- GEMM kernels

__global__ __launch_bounds__(512, 2) void gemm256_gateup(
    const __hip_bfloat16* __restrict__ Xg,
    const __hip_bfloat16* __restrict__ WgTv, const __hip_bfloat16* __restrict__ WuTv,
    const __hip_bfloat16* __restrict__ WgTl, const __hip_bfloat16* __restrict__ WuTl,
    __hip_bfloat16* __restrict__ G, __hip_bfloat16* __restrict__ U,
    const int* __restrict__ counters) {
  extern __shared__ __bf16 smem[];
  const int tid = threadIdx.x, lane = tid & 63, w = tid >> 6;
  const int wm = w >> 2, wn = w & 3;
  const int l15 = lane & 15, l4 = lane >> 4;

  // bijective XCD swizzle (m204 variant)
  const int orig = blockIdx.x;
  const int nwg = gridDim.x;
  const int q = nwg >> 3, r = nwg & 7, xcd = orig & 7;
  const int wg = (xcd < r ? xcd * (q + 1) : r * (q + 1) + (xcd - r) * q) + (orig >> 3);
  const int mt = wg / NTILE_GU, nt = wg % NTILE_GU;
  const int row0 = mt * BM;
  const int nv = counters[0];
  const bool isv = row0 < nv;
  const bool isgate = nt < GATE_TILES;
  const __hip_bfloat16* Bsrc = isgate ? (isv ? WgTv : WgTl) : (isv ? WuTv : WuTl);
  const int ncol0 = (isgate ? nt : nt - GATE_TILES) * 256;
  const __hip_bfloat16* Ag = Xg + (size_t)row0 * D_;
  const __hip_bfloat16* Bg = Bsrc + (size_t)ncol0 * D_;

  f32x4 acc[8][4] = {};
  gemm_kloop(Ag, D_, Bg, D_, NT_GU, smem, acc, wm, wn, l15, l4, w, lane);

  __hip_bfloat16* Out = isgate ? G : U;
#pragma unroll
  for (int m = 0; m < 8; ++m) {
    const int grow = row0 + wm * 128 + m * 16 + l4 * 4;
#pragma unroll
    for (int rr = 0; rr < 4; ++rr) {
      __hip_bfloat16* orow = Out + (size_t)(grow + rr) * F_ + ncol0 + wn * 64 + l15;
#pragma unroll
      for (int n = 0; n < 4; ++n)
        orow[n * 16] = __float2bfloat16(acc[m][n][rr]);
    }
  }
}

__global__ __launch_bounds__(512, 2) void gemm256_down(
    const __hip_bfloat16* __restrict__ H,
    const __hip_bfloat16* __restrict__ WdTv, const __hip_bfloat16* __restrict__ WdTl,
    float* __restrict__ out, const int* __restrict__ counters,
    const int* __restrict__ slot2tok) {
  extern __shared__ __bf16 smem[];
  const int tid = threadIdx.x, lane = tid & 63, w = tid >> 6;
  const int wm = w >> 2, wn = w & 3;
  const int l15 = lane & 15, l4 = lane >> 4;

  const int mt = blockIdx.x / (D_ / 256);
  const int nt = blockIdx.x % (D_ / 256);
  const int z  = blockIdx.y;                 // split-K
  const int row0 = mt * BM;
  const int ncol0 = nt * 256;
  const int ntz = NT_DN / 2;                 // 86
  const int t0 = z * ntz;
  const int nv = counters[0];
  const __hip_bfloat16* Bsrc = (row0 < nv) ? WdTv : WdTl;
  const __hip_bfloat16* Ag = H + (size_t)row0 * F_ + t0 * 64;
  const __hip_bfloat16* Bg = Bsrc + (size_t)ncol0 * F_ + t0 * 64;

  f32x4 acc[8][4] = {};
  gemm_kloop(Ag, F_, Bg, F_, ntz, smem, acc, wm, wn, l15, l4, w, lane);

#pragma unroll
  for (int m = 0; m < 8; ++m) {
    const int slot = row0 + wm * 128 + m * 16 + l4 * 4;
#pragma unroll
    for (int rr = 0; rr < 4; ++rr) {
      const int tok = slot2tok[slot + rr];
      if (tok < 0) continue;
      float* orow = out + (size_t)tok * D_ + ncol0 + wn * 64 + l15;
#pragma unroll
      for (int n = 0; n < 4; ++n)
        atomicAdd(&orow[n * 16], acc[m][n][rr]);
    }
  }
}

// ---------------------------------------------------------------- host

extern "C" void kernel_launch(void* const* d_in, const int* in_sizes, int n_in,
                              void* d_out, int out_size, void* d_ws, size_t ws_size,
                              hipStream_t stream) {
  const float* x   = (const float*)d_in[0];
  const int*   tt  = (const int*)d_in[1];
  const float* wgv = (const float*)d_in[2];
  const float* wuv = (const float*)d_in[3];
  const float* wdv = (const float*)d_in[4];
  const float* wgl = (const float*)d_in[5];
  const float* wul = (const float*)d_in[6];
  const float* wdl = (const float*)d_in[7];
  float* out = (float*)d_out;

  size_t off = 0;
  auto nalign = [](size_t v) { return (v + 255) & ~(size_t)255; };
  const size_t o_cnt = off; off += nalign(2 * sizeof(int));
  const size_t o_s2t = off; off += nalign((size_t)M_ALLOC * sizeof(int));
  const size_t o_xg  = off; off += nalign((size_t)M_ALLOC * D_ * 2);
  const size_t o_g   = off; off += nalign((size_t)M_ALLOC * F_ * 2);
  const size_t o_u   = off; off += nalign((size_t)M_ALLOC * F_ * 2);
  const size_t wbytes = nalign((size_t)D_ * F_ * 2);
  const size_t o_wgv = off; off += wbytes;   // later reused for WdTv
  const size_t o_wuv = off; off += wbytes;   // later reused for WdTl
  const size_t o_wgl = off; off += wbytes;
  const size_t o_wul = off; off += wbytes;

  if (ws_size < off) {
    sentinel_kernel<<<(out_size + 255) / 256, 256, 0, stream>>>(out, out_size);
    return;
  }

  char* ws = (char*)d_ws;
  int* counters = (int*)(ws + o_cnt);
  int* slot2tok = (int*)(ws + o_s2t);
  __hip_bfloat16* Xg  = (__hip_bfloat16*)(ws + o_xg);
  __hip_bfloat16* G   = (__hip_bfloat16*)(ws + o_g);
  __hip_bfloat16* U   = (__hip_bfloat16*)(ws + o_u);
  __hip_bfloat16* WgTv = (__hip_bfloat16*)(ws + o_wgv);
  __hip_bfloat16* WuTv = (__hip_bfloat16*)(ws + o_wuv);
  __hip_bfloat16* WgTl = (__hip_bfloat16*)(ws + o_wgl);
  __hip_bfloat16* WuTl = (__hip_bfloat16*)(ws + o_wul);
  __hip_bfloat16* WdTv = WgTv;  // reuse after gateup consumed gate/up weights
  __hip_bfloat16* WdTl = WuTv;

  hipFuncSetAttribute((const void*)gemm256_gateup,
                      hipFuncAttributeMaxDynamicSharedMemorySize, LDS_BYTES);
  hipFuncSetAttribute((const void*)gemm256_down,
                      hipFuncAttributeMaxDynamicSharedMemorySize, LDS_BYTES);

  hipMemsetAsync(out, 0, (size_t)out_size * sizeof(float), stream);

  init_kernel<<<(M_ALLOC + 255) / 256, 256, 0, stream>>>(counters, slot2tok);
  assign_kernel<<<(M_TOK + 255) / 256, 256, 0, stream>>>(tt, counters, slot2tok);
  gather_cvt<<<M_ALLOC, 256, 0, stream>>>(x, slot2tok, Xg);

  dim3 tb(128);
  dim3 tg_gu(F_ / 64, D_ / 64);   // in [D][F] -> out [F][D]
  transpose_cvt64<<<tg_gu, tb, 0, stream>>>(wgv, WgTv, D_, F_);
  transpose_cvt64<<<tg_gu, tb, 0, stream>>>(wuv, WuTv, D_, F_);
  transpose_cvt64<<<tg_gu, tb, 0, stream>>>(wgl, WgTl, D_, F_);
  transpose_cvt64<<<tg_gu, tb, 0, stream>>>(wul, WuTl, D_, F_);

  gemm256_gateup<<<dim3(NTM * NTILE_GU), 512, LDS_BYTES, stream>>>(
      Xg, WgTv, WuTv, WgTl, WuTl, G, U, counters);

  const long long n8 = (long long)M_ALLOC * F_ / 8;
  silu_mul_kernel<<<(int)((n8 + 255) / 256), 256, 0, stream>>>(G, U, n8);

  dim3 tg_dn(D_ / 64, F_ / 64);   // in [F][D] -> out [D][F]
  transpose_cvt64<<<tg_dn, tb, 0, stream>>>(wdv, WdTv, F_, D_);
  transpose_cvt64<<<tg_dn, tb, 0, stream>>>(wdl, WdTl, F_, D_);

  gemm256_down<<<dim3(NTM * (D_ / 256), 2), 512, LDS_BYTES, stream>>>(
      G, WdTv, WdTl, out, counters, slot2tok);
}

// Round 4
// 1654.715 us; speedup vs baseline: 1.1161x; 1.0257x over previous
//
#include <hip/hip_runtime.h>
#include <hip/hip_bf16.h>

#define B_    2
#define L_    2048
#define D_    4096
#define F_    11008
#define M_TOK (B_ * L_)          // 4096 tokens
#define BM    256
#define M_ALLOC (M_TOK + BM)     // 4352: vision [0,nv), 256-gap, language at top
#define NTM   (M_ALLOC / BM)     // 17 M-tiles
#define NT_GU (D_ / 64)          // 64 K-tiles for gate/up
#define NT_DN (F_ / 64)          // 172 K-tiles for down
#define NTILE_F (F_ / 128)       // 86 N-tiles for fused gate+up (128 cols each)
#define LDS_BYTES 131072

typedef __attribute__((ext_vector_type(8))) __bf16 bf16x8;
typedef __attribute__((ext_vector_type(4))) float  f32x4;
typedef unsigned short ushort_t;
typedef unsigned int   uint_t;

// ---------------------------------------------------------------- primitives

__device__ __forceinline__ void gload_lds16(const void* g, void* l) {
  __builtin_amdgcn_global_load_lds(
      (const __attribute__((address_space(1))) void*)g,
      (__attribute__((address_space(3))) void*)l, 16, 0, 0);
}

#define PH_BAR()  { __builtin_amdgcn_sched_barrier(0); __builtin_amdgcn_s_barrier(); __builtin_amdgcn_sched_barrier(0); }
#define LGKM0()   { asm volatile("s_waitcnt lgkmcnt(0)" ::: "memory"); __builtin_amdgcn_sched_barrier(0); }
#define VM4()     { asm volatile("s_waitcnt vmcnt(4)" ::: "memory"); __builtin_amdgcn_sched_barrier(0); }
#define VM0()     { asm volatile("s_waitcnt vmcnt(0)" ::: "memory"); __builtin_amdgcn_sched_barrier(0); }

__device__ __forceinline__ ushort_t f2bf(float v) {
  union { __hip_bfloat16 h; ushort_t u; } cv;
  cv.h = __float2bfloat16(v);
  return cv.u;
}

// stage one 128x64 bf16 half-tile, inverse-swizzled source -> linear LDS.
// Swizzle (involution): byte ^= (row&7)<<4  <=>  chunk-in-row ^= row&7.
__device__ __forceinline__ void stage_half(const __hip_bfloat16* __restrict__ src, int ldE,
                                           __bf16* ldsb, int w, int lane) {
#pragma unroll
  for (int j = 0; j < 2; ++j) {
    const int ch  = (w * 2 + j) * 64 + lane;   // 16B chunk id, 0..1023
    const int row = ch >> 3;                   // 0..127
    const int cc  = (ch & 7) ^ (row & 7);      // pre-swizzled col chunk
    gload_lds16(src + (size_t)(row * ldE + cc * 8), ldsb + (w * 2 + j) * 512);
  }
}

// swizzled ds_read_b128 of one MFMA fragment from a [rows][64] bf16 region
__device__ __forceinline__ bf16x8 ldfrag(const __bf16* region, int row, int koffb) {
  const int off = ((row << 7) + koffb) ^ ((row & 7) << 4);
  return *(const bf16x8*)((const char*)region + off);
}

__device__ __forceinline__ void mfma_q(f32x4 (&acc)[8][4], int mb, int nb,
                                       const bf16x8 (&af)[4][2], const bf16x8 (&bf)[2][2]) {
#pragma unroll
  for (int mm = 0; mm < 4; ++mm)
#pragma unroll
    for (int nn = 0; nn < 2; ++nn)
#pragma unroll
      for (int ks = 0; ks < 2; ++ks)
        acc[mb + mm][nb + nn] = __builtin_amdgcn_mfma_f32_16x16x32_bf16(
            af[mm][ks], bf[nn][ks], acc[mb + mm][nb + nn], 0, 0, 0);
}

// 256x256 tile, 8 waves (2Mx4N), per-wave 128x64. 4 phases per K-tile.
// (down GEMM; unchanged from round 3, verified)
__device__ __forceinline__ void gemm_kloop(const __hip_bfloat16* __restrict__ Ag, const int ldA,
                                           const __hip_bfloat16* __restrict__ Bg, const int ldB,
                                           const int nt, __bf16* smem, f32x4 (&acc)[8][4],
                                           const int wm, const int wn, const int l15,
                                           const int l4, const int w, const int lane) {
  stage_half(Ag,             ldA, smem,                w, lane);
  stage_half(Ag + 128 * ldA, ldA, smem + 8192,         w, lane);
  stage_half(Bg,             ldB, smem + 16384,        w, lane);
  stage_half(Bg + 128 * ldB, ldB, smem + 24576,        w, lane);
  if (1 < nt) {
    stage_half(Ag + 64,             ldA, smem + 32768,        w, lane);
    stage_half(Ag + 64 + 128 * ldA, ldA, smem + 32768 + 8192, w, lane);
  }
  VM4(); PH_BAR();

  for (int t = 0; t < nt; ++t) {
    __bf16* bufc = smem + (t & 1) * 32768;
    __bf16* bufn = smem + ((t + 1) & 1) * 32768;
    const __bf16* At = bufc;
    const __bf16* Bt = bufc + 16384;
    bf16x8 a0[4][2], a1[4][2], b0[2][2], b1[2][2];

    // ---- P1
#pragma unroll
    for (int i = 0; i < 4; ++i)
#pragma unroll
      for (int ks = 0; ks < 2; ++ks)
        a0[i][ks] = ldfrag(At, wm * 128 + i * 16 + l15, ks * 64 + l4 * 16);
#pragma unroll
    for (int n = 0; n < 2; ++n)
#pragma unroll
      for (int ks = 0; ks < 2; ++ks)
        b0[n][ks] = ldfrag(Bt, wn * 64 + n * 16 + l15, ks * 64 + l4 * 16);
    if (t + 1 < nt) stage_half(Bg + (t + 1) * 64, ldB, bufn + 16384, w, lane);
    PH_BAR(); LGKM0();
    __builtin_amdgcn_s_setprio(1);
    mfma_q(acc, 0, 0, a0, b0);
    __builtin_amdgcn_s_setprio(0);
    PH_BAR();

    // ---- P2
#pragma unroll
    for (int i = 0; i < 4; ++i)
#pragma unroll
      for (int ks = 0; ks < 2; ++ks)
        a1[i][ks] = ldfrag(At, wm * 128 + 64 + i * 16 + l15, ks * 64 + l4 * 16);
    if (t + 1 < nt) stage_half(Bg + (t + 1) * 64 + 128 * ldB, ldB, bufn + 24576, w, lane);
    PH_BAR(); LGKM0();
    __builtin_amdgcn_s_setprio(1);
    mfma_q(acc, 4, 0, a1, b0);
    __builtin_amdgcn_s_setprio(0);
    PH_BAR();

    // ---- P3
#pragma unroll
    for (int n = 0; n < 2; ++n)
#pragma unroll
      for (int ks = 0; ks < 2; ++ks)
        b1[n][ks] = ldfrag(Bt, wn * 64 + 32 + n * 16 + l15, ks * 64 + l4 * 16);
    if (t + 2 < nt) stage_half(Ag + (t + 2) * 64, ldA, bufc, w, lane);
    PH_BAR(); LGKM0();
    __builtin_amdgcn_s_setprio(1);
    mfma_q(acc, 4, 2, a1, b1);
    __builtin_amdgcn_s_setprio(0);
    PH_BAR();

    // ---- P4
    if (t + 2 < nt) stage_half(Ag + (t + 2) * 64 + 128 * ldA, ldA, bufc + 8192, w, lane);
    __builtin_amdgcn_s_setprio(1);
    mfma_q(acc, 0, 2, a0, b1);
    __builtin_amdgcn_s_setprio(0);
    if (t + 2 < nt) { VM4(); } else { VM0(); }   // tail drain
    PH_BAR();
  }
}

// ---------------------------------------------------------------- preprocessing

__global__ void init_kernel(int* counters, int* slot2tok) {
  int i = blockIdx.x * 256 + threadIdx.x;
  if (i < 2) counters[i] = 0;
  if (i < M_ALLOC) slot2tok[i] = -1;
}

__global__ void assign_kernel(const int* __restrict__ tt, int* counters,
                              int* __restrict__ slot2tok) {
  int t = blockIdx.x * 256 + threadIdx.x;
  if (t >= M_TOK) return;
  int l = t & (L_ - 1);
  bool isv = (tt[t] == 1) && (l < L_ - 1) && (tt[t + 1] == 1);
  int slot;
  if (isv) slot = atomicAdd(&counters[0], 1);
  else     slot = M_ALLOC - 1 - atomicAdd(&counters[1], 1);
  slot2tok[slot] = t;
}

__global__ void gather_cvt(const float* __restrict__ x, const int* __restrict__ slot2tok,
                           __hip_bfloat16* __restrict__ xg) {
  const int s = blockIdx.x;
  const int t = slot2tok[s];
  __hip_bfloat16* dst = xg + (size_t)s * D_ + threadIdx.x * 16;
  union { ushort_t h[8]; uint4 v; } p0, p1;
  if (t >= 0) {
    const float4* s4 = (const float4*)(x + (size_t)t * D_ + threadIdx.x * 16);
    float4 a = s4[0], b = s4[1], c = s4[2], d = s4[3];
    float vals[16] = {a.x,a.y,a.z,a.w,b.x,b.y,b.z,b.w,c.x,c.y,c.z,c.w,d.x,d.y,d.z,d.w};
#pragma unroll
    for (int i = 0; i < 8; ++i) p0.h[i] = f2bf(vals[i]);
#pragma unroll
    for (int i = 0; i < 8; ++i) p1.h[i] = f2bf(vals[8 + i]);
  } else {
    p0.v = make_uint4(0, 0, 0, 0);
    p1.v = make_uint4(0, 0, 0, 0);
  }
  *(uint4*)dst = p0.v;
  *(uint4*)(dst + 8) = p1.v;
}

// f32 [R][C] -> bf16 [C][R]; coalesced reads, 64B/lane contiguous writes
__global__ __launch_bounds__(128) void transpose_cvt64(const float* __restrict__ in,
                                                       __hip_bfloat16* __restrict__ out,
                                                       int R, int C) {
  const int c  = threadIdx.x & 63;
  const int rc = threadIdx.x >> 6;
  const int c0 = blockIdx.x * 64;
  const int r0 = blockIdx.y * 64 + rc * 32;
  const float* ip = in + (size_t)r0 * C + c0 + c;
  uint_t pk[16];
#pragma unroll
  for (int j = 0; j < 16; ++j) {
    float v0 = ip[(size_t)(2 * j) * C];
    float v1 = ip[(size_t)(2 * j + 1) * C];
    pk[j] = (uint_t)f2bf(v0) | ((uint_t)f2bf(v1) << 16);
  }
  uint4* op = (uint4*)(out + (size_t)(c0 + c) * R + r0);
#pragma unroll
  for (int k = 0; k < 4; ++k)
    op[k] = make_uint4(pk[4 * k], pk[4 * k + 1], pk[4 * k + 2], pk[4 * k + 3]);
}

__global__ void sentinel_kernel(float* out, int n) {
  int i = blockIdx.x * 256 + threadIdx.x;
  if (i < n) out[i] = 1e30f;
}

// ---------------------------------------------------------------- GEMM 1: fused gate+up+silu
// Tile 256(M) x 128(F-cols); 8 waves 4Mx2N, per-wave 64x64, dual acc (gate,up).
// 2 phases per K-tile, 32 MFMA each.
// LDS (bf16 elems): A[0]:0 A[1]:16384 Bg[0]:32768 Bg[1]:40960 Bu[0]:49152 Bu[1]:57344
// vmcnt ledger (instr units; stage_half = 2): enter t with A(t+1)=4 in flight;
// P1 +Bg(t+1)+Bu(t+1)=8; P2 +A(t+2)=12; tile-end vmcnt(4) retires A(t+1)+Bg+Bu.
// Tails (no A(t+2) staged) drain vmcnt(0).
__global__ __launch_bounds__(512, 2) void gemm256_gateup_fused(
    const __hip_bfloat16* __restrict__ Xg,
    const __hip_bfloat16* __restrict__ WgTv, const __hip_bfloat16* __restrict__ WuTv,
    const __hip_bfloat16* __restrict__ WgTl, const __hip_bfloat16* __restrict__ WuTl,
    __hip_bfloat16* __restrict__ H, const int* __restrict__ counters) {
  extern __shared__ __bf16 smem[];
  const int tid = threadIdx.x, lane = tid & 63, w = tid >> 6;
  const int wm = w >> 1, wn = w & 1;
  const int l15 = lane & 15, l4 = lane >> 4;

  // bijective XCD swizzle
  const int orig = blockIdx.x;
  const int nwg = gridDim.x;
  const int q = nwg >> 3, r = nwg & 7, xcd = orig & 7;
  const int wg = (xcd < r ? xcd * (q + 1) : r * (q + 1) + (xcd - r) * q) + (orig >> 3);
  const int mt = wg / NTILE_F, ntile = wg % NTILE_F;
  const int row0 = mt * BM;
  const int ncol0 = ntile * 128;
  const int nv = counters[0];
  const bool isv = row0 < nv;
  const __hip_bfloat16* Ag   = Xg + (size_t)row0 * D_;
  const __hip_bfloat16* Bg_g = (isv ? WgTv : WgTl) + (size_t)ncol0 * D_;
  const __hip_bfloat16* Bu_g = (isv ? WuTv : WuTl) + (size_t)ncol0 * D_;

  f32x4 accg[4][4] = {};
  f32x4 accu[4][4] = {};
  const int nt = NT_GU;

  // prologue: A(0)h0 A(0)h1 Bg(0) Bu(0) A(1)h0 A(1)h1  -> vmcnt(4)
  stage_half(Ag,                  D_, smem,          w, lane);
  stage_half(Ag + 128 * D_,       D_, smem + 8192,   w, lane);
  stage_half(Bg_g,                D_, smem + 32768,  w, lane);
  stage_half(Bu_g,                D_, smem + 49152,  w, lane);
  stage_half(Ag + 64,             D_, smem + 16384,  w, lane);
  stage_half(Ag + 64 + 128 * D_,  D_, smem + 24576,  w, lane);
  VM4(); PH_BAR();

  for (int t = 0; t < nt; ++t) {
    const int cur = t & 1;
    const __bf16* At  = smem + cur * 16384;
    const __bf16* Bgt = smem + 32768 + cur * 8192;
    const __bf16* But = smem + 49152 + cur * 8192;
    __bf16* nxA  = smem + cur * 16384;             // A(t+2): same buffer, consumed in P1
    __bf16* nxBg = smem + 32768 + (cur ^ 1) * 8192;
    __bf16* nxBu = smem + 49152 + (cur ^ 1) * 8192;
    bf16x8 af[4][2], bg[4][2], bu[4][2];

    // ---- P1: read A + Bg frags; stage Bg(t+1), Bu(t+1); 32 MFMA gate
#pragma unroll
    for (int m = 0; m < 4; ++m)
#pragma unroll
      for (int ks = 0; ks < 2; ++ks)
        af[m][ks] = ldfrag(At, wm * 64 + m * 16 + l15, ks * 64 + l4 * 16);
#pragma unroll
    for (int n = 0; n < 4; ++n)
#pragma unroll
      for (int ks = 0; ks < 2; ++ks)
        bg[n][ks] = ldfrag(Bgt, wn * 64 + n * 16 + l15, ks * 64 + l4 * 16);
    if (t + 1 < nt) {
      stage_half(Bg_g + (t + 1) * 64, D_, nxBg, w, lane);
      stage_half(Bu_g + (t + 1) * 64, D_, nxBu, w, lane);
    }
    PH_BAR(); LGKM0();
    __builtin_amdgcn_s_setprio(1);
#pragma unroll
    for (int m = 0; m < 4; ++m)
#pragma unroll
      for (int n = 0; n < 4; ++n)
#pragma unroll
        for (int ks = 0; ks < 2; ++ks)
          accg[m][n] = __builtin_amdgcn_mfma_f32_16x16x32_bf16(
              af[m][ks], bg[n][ks], accg[m][n], 0, 0, 0);
    __builtin_amdgcn_s_setprio(0);
    PH_BAR();

    // ---- P2: read Bu frags; stage A(t+2); 32 MFMA up
#pragma unroll
    for (int n = 0; n < 4; ++n)
#pragma unroll
      for (int ks = 0; ks < 2; ++ks)
        bu[n][ks] = ldfrag(But, wn * 64 + n * 16 + l15, ks * 64 + l4 * 16);
    if (t + 2 < nt) {
      stage_half(Ag + (t + 2) * 64,            D_, nxA,        w, lane);
      stage_half(Ag + (t + 2) * 64 + 128 * D_, D_, nxA + 8192, w, lane);
    }
    PH_BAR(); LGKM0();
    __builtin_amdgcn_s_setprio(1);
#pragma unroll
    for (int m = 0; m < 4; ++m)
#pragma unroll
      for (int n = 0; n < 4; ++n)
#pragma unroll
        for (int ks = 0; ks < 2; ++ks)
          accu[m][n] = __builtin_amdgcn_mfma_f32_16x16x32_bf16(
              af[m][ks], bu[n][ks], accu[m][n], 0, 0, 0);
    __builtin_amdgcn_s_setprio(0);
    if (t + 2 < nt) { VM4(); } else { VM0(); }
    PH_BAR();
  }

  // epilogue: H = silu(g) * u, bf16
#pragma unroll
  for (int m = 0; m < 4; ++m) {
    const int grow = row0 + wm * 64 + m * 16 + l4 * 4;
#pragma unroll
    for (int rr = 0; rr < 4; ++rr) {
      __hip_bfloat16* orow = H + (size_t)(grow + rr) * F_ + ncol0 + wn * 64 + l15;
#pragma unroll
      for (int n = 0; n < 4; ++n) {
        const float g = accg[m][n][rr];
        const float u = accu[m][n][rr];
        orow[n * 16] = __float2bfloat16(g / (1.0f + __expf(-g)) * u);
      }
    }
  }
}

// ---------------------------------------------------------------- GEMM 2: down + scatter

__global__ __launch_bounds__(512, 2) void gemm256_down(
    const __hip_bfloat16* __restrict__ H,
    const __hip_bfloat16* __restrict__ WdTv, const __hip_bfloat16* __restrict__ WdTl,
    float* __restrict__ out, const int* __restrict__ counters,
    const int* __restrict__ slot2tok) {
  extern __shared__ __bf16 smem[];
  const int tid = threadIdx.x, lane = tid & 63, w = tid >> 6;
  const int wm = w >> 2, wn = w & 3;
  const int l15 = lane & 15, l4 = lane >> 4;

  const int mt = blockIdx.x / (D_ / 256);
  const int nt = blockIdx.x % (D_ / 256);
  const int z  = blockIdx.y;                 // split-K
  const int row0 = mt * BM;
  const int ncol0 = nt * 256;
  const int ntz = NT_DN / 2;                 // 86
  const int t0 = z * ntz;
  const int nv = counters[0];
  const __hip_bfloat16* Bsrc = (row0 < nv) ? WdTv : WdTl;
  const __hip_bfloat16* Ag = H + (size_t)row0 * F_ + t0 * 64;
  const __hip_bfloat16* Bg = Bsrc + (size_t)ncol0 * F_ + t0 * 64;

  f32x4 acc[8][4] = {};
  gemm_kloop(Ag, F_, Bg, F_, ntz, smem, acc, wm, wn, l15, l4, w, lane);

#pragma unroll
  for (int m = 0; m < 8; ++m) {
    const int slot = row0 + wm * 128 + m * 16 + l4 * 4;
#pragma unroll
    for (int rr = 0; rr < 4; ++rr) {
      const int tok = slot2tok[slot + rr];
      if (tok < 0) continue;
      float* orow = out + (size_t)tok * D_ + ncol0 + wn * 64 + l15;
#pragma unroll
      for (int n = 0; n < 4; ++n)
        atomicAdd(&orow[n * 16], acc[m][n][rr]);
    }
  }
}

// ---------------------------------------------------------------- host

extern "C" void kernel_launch(void* const* d_in, const int* in_sizes, int n_in,
                              void* d_out, int out_size, void* d_ws, size_t ws_size,
                              hipStream_t stream) {
  const float* x   = (const float*)d_in[0];
  const int*   tt  = (const int*)d_in[1];
  const float* wgv = (const float*)d_in[2];
  const float* wuv = (const float*)d_in[3];
  const float* wdv = (const float*)d_in[4];
  const float* wgl = (const float*)d_in[5];
  const float* wul = (const float*)d_in[6];
  const float* wdl = (const float*)d_in[7];
  float* out = (float*)d_out;

  size_t off = 0;
  auto nalign = [](size_t v) { return (v + 255) & ~(size_t)255; };
  const size_t o_cnt = off; off += nalign(2 * sizeof(int));
  const size_t o_s2t = off; off += nalign((size_t)M_ALLOC * sizeof(int));
  const size_t o_xg  = off; off += nalign((size_t)M_ALLOC * D_ * 2);
  const size_t o_h   = off; off += nalign((size_t)M_ALLOC * F_ * 2);
  const size_t wbytes = nalign((size_t)D_ * F_ * 2);
  const size_t o_wgv = off; off += wbytes;   // later reused for WdTv
  const size_t o_wuv = off; off += wbytes;   // later reused for WdTl
  const size_t o_wgl = off; off += wbytes;
  const size_t o_wul = off; off += wbytes;

  if (ws_size < off) {
    sentinel_kernel<<<(out_size + 255) / 256, 256, 0, stream>>>(out, out_size);
    return;
  }

  char* ws = (char*)d_ws;
  int* counters = (int*)(ws + o_cnt);
  int* slot2tok = (int*)(ws + o_s2t);
  __hip_bfloat16* Xg  = (__hip_bfloat16*)(ws + o_xg);
  __hip_bfloat16* H   = (__hip_bfloat16*)(ws + o_h);
  __hip_bfloat16* WgTv = (__hip_bfloat16*)(ws + o_wgv);
  __hip_bfloat16* WuTv = (__hip_bfloat16*)(ws + o_wuv);
  __hip_bfloat16* WgTl = (__hip_bfloat16*)(ws + o_wgl);
  __hip_bfloat16* WuTl = (__hip_bfloat16*)(ws + o_wul);
  __hip_bfloat16* WdTv = WgTv;  // reuse after gateup consumed gate/up weights
  __hip_bfloat16* WdTl = WuTv;

  hipFuncSetAttribute((const void*)gemm256_gateup_fused,
                      hipFuncAttributeMaxDynamicSharedMemorySize, LDS_BYTES);
  hipFuncSetAttribute((const void*)gemm256_down,
                      hipFuncAttributeMaxDynamicSharedMemorySize, LDS_BYTES);

  hipMemsetAsync(out, 0, (size_t)out_size * sizeof(float), stream);

  init_kernel<<<(M_ALLOC + 255) / 256, 256, 0, stream>>>(counters, slot2tok);
  assign_kernel<<<(M_TOK + 255) / 256, 256, 0, stream>>>(tt, counters, slot2tok);
  gather_cvt<<<M_ALLOC, 256, 0, stream>>>(x, slot2tok, Xg);

  dim3 tb(128);
  dim3 tg_gu(F_ / 64, D_ / 64);   // in [D][F] -> out [F][D]
  transpose_cvt64<<<tg_gu, tb, 0, stream>>>(wgv, WgTv, D_, F_);
  transpose_cvt64<<<tg_gu, tb, 0, stream>>>(wuv, WuTv, D_, F_);
  transpose_cvt64<<<tg_gu, tb, 0, stream>>>(wgl, WgTl, D_, F_);
  transpose_cvt64<<<tg_gu, tb, 0, stream>>>(wul, WuTl, D_, F_);

  gemm256_gateup_fused<<<dim3(NTM * NTILE_F), 512, LDS_BYTES, stream>>>(
      Xg, WgTv, WuTv, WgTl, WuTl, H, counters);

  dim3 tg_dn(D_ / 64, F_ / 64);   // in [F][D] -> out [D][F]
  transpose_cvt64<<<tg_dn, tb, 0, stream>>>(wdv, WdTv, F_, D_);
  transpose_cvt64<<<tg_dn, tb, 0, stream>>>(wdl, WdTl, F_, D_);

  gemm256_down<<<dim3(NTM * (D_ / 256), 2), 512, LDS_BYTES, stream>>>(
      H, WdTv, WdTl, out, counters, slot2tok);
}

// Round 5
// 1635.799 us; speedup vs baseline: 1.1290x; 1.0116x over previous
//
#include <hip/hip_runtime.h>
#include <hip/hip_bf16.h>

#define B_    2
#define L_    2048
#define D_    4096
#define F_    11008
#define M_TOK (B_ * L_)          // 4096 tokens
#define BM    256
#define M_ALLOC (M_TOK + BM)     // 4352: vision [0,nv), 256-gap, language at top
#define NTM   (M_ALLOC / BM)     // 17 M-tiles
#define NT_GU (D_ / 64)          // 64 K-tiles for gate/up
#define NT_DN (F_ / 64)          // 172 K-tiles for down
#define NTILE_F (F_ / 128)       // 86 N-tiles for fused gate+up (128 cols each)
#define SPLITK_DN 4
#define LDS_BYTES 131072

typedef __attribute__((ext_vector_type(8))) __bf16 bf16x8;
typedef __attribute__((ext_vector_type(4))) float  f32x4;
typedef unsigned short ushort_t;
typedef unsigned int   uint_t;

// ---------------------------------------------------------------- primitives

__device__ __forceinline__ void gload_lds16(const void* g, void* l) {
  __builtin_amdgcn_global_load_lds(
      (const __attribute__((address_space(1))) void*)g,
      (__attribute__((address_space(3))) void*)l, 16, 0, 0);
}

#define PH_BAR()  { __builtin_amdgcn_sched_barrier(0); __builtin_amdgcn_s_barrier(); __builtin_amdgcn_sched_barrier(0); }
#define LGKM0()   { asm volatile("s_waitcnt lgkmcnt(0)" ::: "memory"); __builtin_amdgcn_sched_barrier(0); }
#define VM4()     { asm volatile("s_waitcnt vmcnt(4)" ::: "memory"); __builtin_amdgcn_sched_barrier(0); }
#define VM0()     { asm volatile("s_waitcnt vmcnt(0)" ::: "memory"); __builtin_amdgcn_sched_barrier(0); }

__device__ __forceinline__ ushort_t f2bf(float v) {
  union { __hip_bfloat16 h; ushort_t u; } cv;
  cv.h = __float2bfloat16(v);
  return cv.u;
}

// bijective XCD swizzle (m204)
__device__ __forceinline__ int xcd_swz(int orig, int nwg) {
  const int q = nwg >> 3, r = nwg & 7, xcd = orig & 7;
  return (xcd < r ? xcd * (q + 1) : r * (q + 1) + (xcd - r) * q) + (orig >> 3);
}

// stage one 128x64 bf16 half-tile, inverse-swizzled source -> linear LDS.
// Swizzle (involution): byte ^= (row&7)<<4  <=>  chunk-in-row ^= row&7.
__device__ __forceinline__ void stage_half(const __hip_bfloat16* __restrict__ src, int ldE,
                                           __bf16* ldsb, int w, int lane) {
#pragma unroll
  for (int j = 0; j < 2; ++j) {
    const int ch  = (w * 2 + j) * 64 + lane;   // 16B chunk id, 0..1023
    const int row = ch >> 3;                   // 0..127
    const int cc  = (ch & 7) ^ (row & 7);      // pre-swizzled col chunk
    gload_lds16(src + (size_t)(row * ldE + cc * 8), ldsb + (w * 2 + j) * 512);
  }
}

// swizzled ds_read_b128 of one MFMA fragment from a [rows][64] bf16 region
__device__ __forceinline__ bf16x8 ldfrag(const __bf16* region, int row, int koffb) {
  const int off = ((row << 7) + koffb) ^ ((row & 7) << 4);
  return *(const bf16x8*)((const char*)region + off);
}

__device__ __forceinline__ void mfma_q(f32x4 (&acc)[8][4], int mb, int nb,
                                       const bf16x8 (&af)[4][2], const bf16x8 (&bf)[2][2]) {
#pragma unroll
  for (int mm = 0; mm < 4; ++mm)
#pragma unroll
    for (int nn = 0; nn < 2; ++nn)
#pragma unroll
      for (int ks = 0; ks < 2; ++ks)
        acc[mb + mm][nb + nn] = __builtin_amdgcn_mfma_f32_16x16x32_bf16(
            af[mm][ks], bf[nn][ks], acc[mb + mm][nb + nn], 0, 0, 0);
}

// 256x256 tile, 8 waves (2Mx4N), per-wave 128x64. 4 phases per K-tile.
// (down GEMM; verified rounds 3-4)
__device__ __forceinline__ void gemm_kloop(const __hip_bfloat16* __restrict__ Ag, const int ldA,
                                           const __hip_bfloat16* __restrict__ Bg, const int ldB,
                                           const int nt, __bf16* smem, f32x4 (&acc)[8][4],
                                           const int wm, const int wn, const int l15,
                                           const int l4, const int w, const int lane) {
  stage_half(Ag,             ldA, smem,                w, lane);
  stage_half(Ag + 128 * ldA, ldA, smem + 8192,         w, lane);
  stage_half(Bg,             ldB, smem + 16384,        w, lane);
  stage_half(Bg + 128 * ldB, ldB, smem + 24576,        w, lane);
  if (1 < nt) {
    stage_half(Ag + 64,             ldA, smem + 32768,        w, lane);
    stage_half(Ag + 64 + 128 * ldA, ldA, smem + 32768 + 8192, w, lane);
  }
  VM4(); PH_BAR();

  for (int t = 0; t < nt; ++t) {
    __bf16* bufc = smem + (t & 1) * 32768;
    __bf16* bufn = smem + ((t + 1) & 1) * 32768;
    const __bf16* At = bufc;
    const __bf16* Bt = bufc + 16384;
    bf16x8 a0[4][2], a1[4][2], b0[2][2], b1[2][2];

    // ---- P1
#pragma unroll
    for (int i = 0; i < 4; ++i)
#pragma unroll
      for (int ks = 0; ks < 2; ++ks)
        a0[i][ks] = ldfrag(At, wm * 128 + i * 16 + l15, ks * 64 + l4 * 16);
#pragma unroll
    for (int n = 0; n < 2; ++n)
#pragma unroll
      for (int ks = 0; ks < 2; ++ks)
        b0[n][ks] = ldfrag(Bt, wn * 64 + n * 16 + l15, ks * 64 + l4 * 16);
    if (t + 1 < nt) stage_half(Bg + (t + 1) * 64, ldB, bufn + 16384, w, lane);
    PH_BAR(); LGKM0();
    __builtin_amdgcn_s_setprio(1);
    mfma_q(acc, 0, 0, a0, b0);
    __builtin_amdgcn_s_setprio(0);
    PH_BAR();

    // ---- P2
#pragma unroll
    for (int i = 0; i < 4; ++i)
#pragma unroll
      for (int ks = 0; ks < 2; ++ks)
        a1[i][ks] = ldfrag(At, wm * 128 + 64 + i * 16 + l15, ks * 64 + l4 * 16);
    if (t + 1 < nt) stage_half(Bg + (t + 1) * 64 + 128 * ldB, ldB, bufn + 24576, w, lane);
    PH_BAR(); LGKM0();
    __builtin_amdgcn_s_setprio(1);
    mfma_q(acc, 4, 0, a1, b0);
    __builtin_amdgcn_s_setprio(0);
    PH_BAR();

    // ---- P3
#pragma unroll
    for (int n = 0; n < 2; ++n)
#pragma unroll
      for (int ks = 0; ks < 2; ++ks)
        b1[n][ks] = ldfrag(Bt, wn * 64 + 32 + n * 16 + l15, ks * 64 + l4 * 16);
    if (t + 2 < nt) stage_half(Ag + (t + 2) * 64, ldA, bufc, w, lane);
    PH_BAR(); LGKM0();
    __builtin_amdgcn_s_setprio(1);
    mfma_q(acc, 4, 2, a1, b1);
    __builtin_amdgcn_s_setprio(0);
    PH_BAR();

    // ---- P4
    if (t + 2 < nt) stage_half(Ag + (t + 2) * 64 + 128 * ldA, ldA, bufc + 8192, w, lane);
    __builtin_amdgcn_s_setprio(1);
    mfma_q(acc, 0, 2, a0, b1);
    __builtin_amdgcn_s_setprio(0);
    if (t + 2 < nt) { VM4(); } else { VM0(); }   // tail drain
    PH_BAR();
  }
}

// ---------------------------------------------------------------- preprocessing

__global__ void init_kernel(int* counters, int* slot2tok) {
  int i = blockIdx.x * 256 + threadIdx.x;
  if (i < 2) counters[i] = 0;
  if (i < M_ALLOC) slot2tok[i] = -1;
}

__global__ void assign_kernel(const int* __restrict__ tt, int* counters,
                              int* __restrict__ slot2tok) {
  int t = blockIdx.x * 256 + threadIdx.x;
  if (t >= M_TOK) return;
  int l = t & (L_ - 1);
  bool isv = (tt[t] == 1) && (l < L_ - 1) && (tt[t + 1] == 1);
  int slot;
  if (isv) slot = atomicAdd(&counters[0], 1);
  else     slot = M_ALLOC - 1 - atomicAdd(&counters[1], 1);
  slot2tok[slot] = t;
}

__global__ void gather_cvt(const float* __restrict__ x, const int* __restrict__ slot2tok,
                           __hip_bfloat16* __restrict__ xg) {
  const int s = blockIdx.x;
  const int t = slot2tok[s];
  __hip_bfloat16* dst = xg + (size_t)s * D_ + threadIdx.x * 16;
  union { ushort_t h[8]; uint4 v; } p0, p1;
  if (t >= 0) {
    const float4* s4 = (const float4*)(x + (size_t)t * D_ + threadIdx.x * 16);
    float4 a = s4[0], b = s4[1], c = s4[2], d = s4[3];
    float vals[16] = {a.x,a.y,a.z,a.w,b.x,b.y,b.z,b.w,c.x,c.y,c.z,c.w,d.x,d.y,d.z,d.w};
#pragma unroll
    for (int i = 0; i < 8; ++i) p0.h[i] = f2bf(vals[i]);
#pragma unroll
    for (int i = 0; i < 8; ++i) p1.h[i] = f2bf(vals[8 + i]);
  } else {
    p0.v = make_uint4(0, 0, 0, 0);
    p1.v = make_uint4(0, 0, 0, 0);
  }
  *(uint4*)dst = p0.v;
  *(uint4*)(dst + 8) = p1.v;
}

// f32 [R][C] -> bf16 [C][R]; coalesced reads, 64B/lane contiguous writes
__global__ __launch_bounds__(128) void transpose_cvt64(const float* __restrict__ in,
                                                       __hip_bfloat16* __restrict__ out,
                                                       int R, int C) {
  const int c  = threadIdx.x & 63;
  const int rc = threadIdx.x >> 6;
  const int c0 = blockIdx.x * 64;
  const int r0 = blockIdx.y * 64 + rc * 32;
  const float* ip = in + (size_t)r0 * C + c0 + c;
  uint_t pk[16];
#pragma unroll
  for (int j = 0; j < 16; ++j) {
    float v0 = ip[(size_t)(2 * j) * C];
    float v1 = ip[(size_t)(2 * j + 1) * C];
    pk[j] = (uint_t)f2bf(v0) | ((uint_t)f2bf(v1) << 16);
  }
  uint4* op = (uint4*)(out + (size_t)(c0 + c) * R + r0);
#pragma unroll
  for (int k = 0; k < 4; ++k)
    op[k] = make_uint4(pk[4 * k], pk[4 * k + 1], pk[4 * k + 2], pk[4 * k + 3]);
}

__global__ void sentinel_kernel(float* out, int n) {
  int i = blockIdx.x * 256 + threadIdx.x;
  if (i < n) out[i] = 1e30f;
}

// ---------------------------------------------------------------- GEMM 1: fused gate+up+silu
// Tile 256(M) x 128(F-cols); 8 waves 4Mx2N, per-wave 64x64 dual acc (gate,up).
// 4 phases per K-tile, 16 MFMA each (fine interleave, T3-conformant):
//  P1: ds_read af(8)+bg(8); stage Bg(t+1); MFMA gate m01
//  P2: ds_read (none new);                MFMA gate m23   [af m23 read in P2]
//  P3: ds_read bu(8);       stage A(t+2)h0; MFMA up m01
//  P4: register-only;       stage A(t+2)h1; MFMA up m23; tile-end vmcnt
// vmcnt ledger identical to round 4 (verified): enter tile with A(t+1)=4 in
// flight; +Bg(2)+Bu(2)+Ah0(2)+Ah1(2)=12; vmcnt(4) retires A(t+1)+Bg+Bu.
// Tails (no A(t+2) staged) drain vmcnt(0).
__global__ __launch_bounds__(512, 2) void gemm256_gateup_fused(
    const __hip_bfloat16* __restrict__ Xg,
    const __hip_bfloat16* __restrict__ WgTv, const __hip_bfloat16* __restrict__ WuTv,
    const __hip_bfloat16* __restrict__ WgTl, const __hip_bfloat16* __restrict__ WuTl,
    __hip_bfloat16* __restrict__ H, const int* __restrict__ counters) {
  extern __shared__ __bf16 smem[];
  const int tid = threadIdx.x, lane = tid & 63, w = tid >> 6;
  const int wm = w >> 1, wn = w & 1;
  const int l15 = lane & 15, l4 = lane >> 4;

  const int wg = xcd_swz(blockIdx.x, gridDim.x);
  const int mt = wg % NTM, ntile = wg / NTM;   // N-major: consecutive wg share B-panel
  const int row0 = mt * BM;
  const int ncol0 = ntile * 128;
  const int nv = counters[0];
  const bool isv = row0 < nv;
  const __hip_bfloat16* Ag   = Xg + (size_t)row0 * D_;
  const __hip_bfloat16* Bg_g = (isv ? WgTv : WgTl) + (size_t)ncol0 * D_;
  const __hip_bfloat16* Bu_g = (isv ? WuTv : WuTl) + (size_t)ncol0 * D_;

  f32x4 accg[4][4] = {};
  f32x4 accu[4][4] = {};
  const int nt = NT_GU;

  // prologue: A(0)h0 A(0)h1 Bg(0) Bu(0) A(1)h0 A(1)h1  -> vmcnt(4)
  stage_half(Ag,                  D_, smem,          w, lane);
  stage_half(Ag + 128 * D_,       D_, smem + 8192,   w, lane);
  stage_half(Bg_g,                D_, smem + 32768,  w, lane);
  stage_half(Bu_g,                D_, smem + 49152,  w, lane);
  stage_half(Ag + 64,             D_, smem + 16384,  w, lane);
  stage_half(Ag + 64 + 128 * D_,  D_, smem + 24576,  w, lane);
  VM4(); PH_BAR();

  for (int t = 0; t < nt; ++t) {
    const int cur = t & 1;
    const __bf16* At  = smem + cur * 16384;            // [256][64] contiguous
    const __bf16* Bgt = smem + 32768 + cur * 8192;
    const __bf16* But = smem + 49152 + cur * 8192;
    __bf16* nxA  = smem + cur * 16384;                 // A(t+2): same buffer
    __bf16* nxBg = smem + 32768 + (cur ^ 1) * 8192;
    __bf16* nxBu = smem + 49152 + (cur ^ 1) * 8192;
    bf16x8 af[4][2], bb[4][2];

    // ---- P1: read af m01 + all bg; stage Bg(t+1); MFMA gate m01
#pragma unroll
    for (int m = 0; m < 2; ++m)
#pragma unroll
      for (int ks = 0; ks < 2; ++ks)
        af[m][ks] = ldfrag(At, wm * 64 + m * 16 + l15, ks * 64 + l4 * 16);
#pragma unroll
    for (int n = 0; n < 4; ++n)
#pragma unroll
      for (int ks = 0; ks < 2; ++ks)
        bb[n][ks] = ldfrag(Bgt, wn * 64 + n * 16 + l15, ks * 64 + l4 * 16);
    if (t + 1 < nt) stage_half(Bg_g + (t + 1) * 64, D_, nxBg, w, lane);
    PH_BAR(); LGKM0();
    __builtin_amdgcn_s_setprio(1);
#pragma unroll
    for (int m = 0; m < 2; ++m)
#pragma unroll
      for (int n = 0; n < 4; ++n)
#pragma unroll
        for (int ks = 0; ks < 2; ++ks)
          accg[m][n] = __builtin_amdgcn_mfma_f32_16x16x32_bf16(
              af[m][ks], bb[n][ks], accg[m][n], 0, 0, 0);
    __builtin_amdgcn_s_setprio(0);
    PH_BAR();

    // ---- P2: read af m23; stage Bu(t+1); MFMA gate m23
#pragma unroll
    for (int m = 2; m < 4; ++m)
#pragma unroll
      for (int ks = 0; ks < 2; ++ks)
        af[m][ks] = ldfrag(At, wm * 64 + m * 16 + l15, ks * 64 + l4 * 16);
    if (t + 1 < nt) stage_half(Bu_g + (t + 1) * 64, D_, nxBu, w, lane);
    PH_BAR(); LGKM0();
    __builtin_amdgcn_s_setprio(1);
#pragma unroll
    for (int m = 2; m < 4; ++m)
#pragma unroll
      for (int n = 0; n < 4; ++n)
#pragma unroll
        for (int ks = 0; ks < 2; ++ks)
          accg[m][n] = __builtin_amdgcn_mfma_f32_16x16x32_bf16(
              af[m][ks], bb[n][ks], accg[m][n], 0, 0, 0);
    __builtin_amdgcn_s_setprio(0);
    PH_BAR();

    // ---- P3: read all bu (overwrite bb); stage A(t+2)h0; MFMA up m01
#pragma unroll
    for (int n = 0; n < 4; ++n)
#pragma unroll
      for (int ks = 0; ks < 2; ++ks)
        bb[n][ks] = ldfrag(But, wn * 64 + n * 16 + l15, ks * 64 + l4 * 16);
    if (t + 2 < nt) stage_half(Ag + (t + 2) * 64, D_, nxA, w, lane);
    PH_BAR(); LGKM0();
    __builtin_amdgcn_s_setprio(1);
#pragma unroll
    for (int m = 0; m < 2; ++m)
#pragma unroll
      for (int n = 0; n < 4; ++n)
#pragma unroll
        for (int ks = 0; ks < 2; ++ks)
          accu[m][n] = __builtin_amdgcn_mfma_f32_16x16x32_bf16(
              af[m][ks], bb[n][ks], accu[m][n], 0, 0, 0);
    __builtin_amdgcn_s_setprio(0);
    PH_BAR();

    // ---- P4: register-only MFMA up m23; stage A(t+2)h1; tile-end vmcnt
    if (t + 2 < nt) stage_half(Ag + (t + 2) * 64 + 128 * D_, D_, nxA + 8192, w, lane);
    __builtin_amdgcn_s_setprio(1);
#pragma unroll
    for (int m = 2; m < 4; ++m)
#pragma unroll
      for (int n = 0; n < 4; ++n)
#pragma unroll
        for (int ks = 0; ks < 2; ++ks)
          accu[m][n] = __builtin_amdgcn_mfma_f32_16x16x32_bf16(
              af[m][ks], bb[n][ks], accu[m][n], 0, 0, 0);
    __builtin_amdgcn_s_setprio(0);
    if (t + 2 < nt) { VM4(); } else { VM0(); }
    PH_BAR();
  }

  // epilogue: H = silu(g) * u, bf16
#pragma unroll
  for (int m = 0; m < 4; ++m) {
    const int grow = row0 + wm * 64 + m * 16 + l4 * 4;
#pragma unroll
    for (int rr = 0; rr < 4; ++rr) {
      __hip_bfloat16* orow = H + (size_t)(grow + rr) * F_ + ncol0 + wn * 64 + l15;
#pragma unroll
      for (int n = 0; n < 4; ++n) {
        const float g = accg[m][n][rr];
        const float u = accu[m][n][rr];
        orow[n * 16] = __float2bfloat16(g / (1.0f + __expf(-g)) * u);
      }
    }
  }
}

// ---------------------------------------------------------------- GEMM 2: down + scatter

__global__ __launch_bounds__(512, 2) void gemm256_down(
    const __hip_bfloat16* __restrict__ H,
    const __hip_bfloat16* __restrict__ WdTv, const __hip_bfloat16* __restrict__ WdTl,
    float* __restrict__ out, const int* __restrict__ counters,
    const int* __restrict__ slot2tok) {
  extern __shared__ __bf16 smem[];
  const int tid = threadIdx.x, lane = tid & 63, w = tid >> 6;
  const int wm = w >> 2, wn = w & 3;
  const int l15 = lane & 15, l4 = lane >> 4;

  const int wg = xcd_swz(blockIdx.x, gridDim.x);
  const int mt = wg % NTM, nt = wg / NTM;    // N-major
  const int z  = blockIdx.y;                 // split-K
  const int row0 = mt * BM;
  const int ncol0 = nt * 256;
  const int ntz = NT_DN / SPLITK_DN;         // 43
  const int t0 = z * ntz;
  const int nv = counters[0];
  const __hip_bfloat16* Bsrc = (row0 < nv) ? WdTv : WdTl;
  const __hip_bfloat16* Ag = H + (size_t)row0 * F_ + t0 * 64;
  const __hip_bfloat16* Bg = Bsrc + (size_t)ncol0 * F_ + t0 * 64;

  f32x4 acc[8][4] = {};
  gemm_kloop(Ag, F_, Bg, F_, ntz, smem, acc, wm, wn, l15, l4, w, lane);

#pragma unroll
  for (int m = 0; m < 8; ++m) {
    const int slot = row0 + wm * 128 + m * 16 + l4 * 4;
#pragma unroll
    for (int rr = 0; rr < 4; ++rr) {
      const int tok = slot2tok[slot + rr];
      if (tok < 0) continue;
      float* orow = out + (size_t)tok * D_ + ncol0 + wn * 64 + l15;
#pragma unroll
      for (int n = 0; n < 4; ++n)
        atomicAdd(&orow[n * 16], acc[m][n][rr]);
    }
  }
}

// ---------------------------------------------------------------- host

extern "C" void kernel_launch(void* const* d_in, const int* in_sizes, int n_in,
                              void* d_out, int out_size, void* d_ws, size_t ws_size,
                              hipStream_t stream) {
  const float* x   = (const float*)d_in[0];
  const int*   tt  = (const int*)d_in[1];
  const float* wgv = (const float*)d_in[2];
  const float* wuv = (const float*)d_in[3];
  const float* wdv = (const float*)d_in[4];
  const float* wgl = (const float*)d_in[5];
  const float* wul = (const float*)d_in[6];
  const float* wdl = (const float*)d_in[7];
  float* out = (float*)d_out;

  size_t off = 0;
  auto nalign = [](size_t v) { return (v + 255) & ~(size_t)255; };
  const size_t o_cnt = off; off += nalign(2 * sizeof(int));
  const size_t o_s2t = off; off += nalign((size_t)M_ALLOC * sizeof(int));
  const size_t o_xg  = off; off += nalign((size_t)M_ALLOC * D_ * 2);
  const size_t o_h   = off; off += nalign((size_t)M_ALLOC * F_ * 2);
  const size_t wbytes = nalign((size_t)D_ * F_ * 2);
  const size_t o_wgv = off; off += wbytes;   // later reused for WdTv
  const size_t o_wuv = off; off += wbytes;   // later reused for WdTl
  const size_t o_wgl = off; off += wbytes;
  const size_t o_wul = off; off += wbytes;

  if (ws_size < off) {
    sentinel_kernel<<<(out_size + 255) / 256, 256, 0, stream>>>(out, out_size);
    return;
  }

  char* ws = (char*)d_ws;
  int* counters = (int*)(ws + o_cnt);
  int* slot2tok = (int*)(ws + o_s2t);
  __hip_bfloat16* Xg  = (__hip_bfloat16*)(ws + o_xg);
  __hip_bfloat16* H   = (__hip_bfloat16*)(ws + o_h);
  __hip_bfloat16* WgTv = (__hip_bfloat16*)(ws + o_wgv);
  __hip_bfloat16* WuTv = (__hip_bfloat16*)(ws + o_wuv);
  __hip_bfloat16* WgTl = (__hip_bfloat16*)(ws + o_wgl);
  __hip_bfloat16* WuTl = (__hip_bfloat16*)(ws + o_wul);
  __hip_bfloat16* WdTv = WgTv;  // reuse after gateup consumed gate/up weights
  __hip_bfloat16* WdTl = WuTv;

  hipFuncSetAttribute((const void*)gemm256_gateup_fused,
                      hipFuncAttributeMaxDynamicSharedMemorySize, LDS_BYTES);
  hipFuncSetAttribute((const void*)gemm256_down,
                      hipFuncAttributeMaxDynamicSharedMemorySize, LDS_BYTES);

  hipMemsetAsync(out, 0, (size_t)out_size * sizeof(float), stream);

  init_kernel<<<(M_ALLOC + 255) / 256, 256, 0, stream>>>(counters, slot2tok);
  assign_kernel<<<(M_TOK + 255) / 256, 256, 0, stream>>>(tt, counters, slot2tok);
  gather_cvt<<<M_ALLOC, 256, 0, stream>>>(x, slot2tok, Xg);

  dim3 tb(128);
  dim3 tg_gu(F_ / 64, D_ / 64);   // in [D][F] -> out [F][D]
  transpose_cvt64<<<tg_gu, tb, 0, stream>>>(wgv, WgTv, D_, F_);
  transpose_cvt64<<<tg_gu, tb, 0, stream>>>(wuv, WuTv, D_, F_);
  transpose_cvt64<<<tg_gu, tb, 0, stream>>>(wgl, WgTl, D_, F_);
  transpose_cvt64<<<tg_gu, tb, 0, stream>>>(wul, WuTl, D_, F_);

  gemm256_gateup_fused<<<dim3(NTM * NTILE_F), 512, LDS_BYTES, stream>>>(
      Xg, WgTv, WuTv, WgTl, WuTl, H, counters);

  dim3 tg_dn(D_ / 64, F_ / 64);   // in [F][D] -> out [D][F]
  transpose_cvt64<<<tg_dn, tb, 0, stream>>>(wdv, WdTv, F_, D_);
  transpose_cvt64<<<tg_dn, tb, 0, stream>>>(wdl, WdTl, F_, D_);

  gemm256_down<<<dim3(NTM * (D_ / 256), SPLITK_DN), 512, LDS_BYTES, stream>>>(
      H, WdTv, WdTl, out, counters, slot2tok);
}